// Round 13
// baseline (215.300 us; speedup 1.0000x reference)
//
#include <hip/hip_runtime.h>
#include <cstddef>
#include <cmath>

// ---------------------------------------------------------------------------
// SWGAT layer:
//   z = h @ W_fc.T                       [N,128]
//   e = leaky_relu(a1[src] + a2[dst]);  e==0 -> -1000
//   segment softmax over dst, out[w] = sum alpha * z[src]
// R19: single change vs R18 (best, 213.7us): scatter geometry. 977 one-shot
//      trailing scatter blocks -> 1368 blocks over 512 residency slots = 2.7
//      rounds, ~850 blocks as a serial ~1us-lived tail (launch churn). R10's
//      co-residency test was confounded by a gemm rewrite (FETCH doubled);
//      this isolates it on the proven base: SB=121 -> 391+121 = 512 blocks =
//      EXACTLY one round, all blocks resident at t=0, scatter grid-strides
//      ~8 edges/thread with depth-2 atomic pipeline (R11-proven semantics).
//      gemm + agg byte-identical to R18. Fork: tail-churn real -> fused
//      73->~60, total ~200; neutral -> structure converged (plateau is the
//      environment-level uniform multiplier seen all session).
// ---------------------------------------------------------------------------

#define IN_DIM  256
#define OUT_DIM 128
#define CAP     64      // max edges kept per dst (Poisson(10) => max deg ~30)

typedef _Float16 half2_t __attribute__((ext_vector_type(2)));
typedef _Float16 half8_t __attribute__((ext_vector_type(8)));
typedef float    f32x4   __attribute__((ext_vector_type(4)));

// --- K1: fused Bconv + gemm + scatter ---------------------------------------
// Blocks [0, GB): gemm. 512 thr = 8 waves, tile 256 rows x 128 cols. B staged
//   by reading wfc fp32 (L2-hot after first blocks), converting to f16 and
//   ds_write-ing swizzled granules: granule g = n*32+(kb^(n&7)) holds
//   W[n][kb*8..+7]. Wave w owns rows {w*16..+15},{128+w*16..+15}; depth-3
//   rolling A prefetch; one barrier.
// Blocks [GB, GB+SB): scatter, grid-stride ~8 edges/thread, depth-2 atomic
//   pipeline, poison-baseline slot index.
__global__ __launch_bounds__(512, 4) void gemm_scatter_kernel(
        const float* __restrict__ h, const float* __restrict__ wfc,
        const float* __restrict__ wattn, _Float16* __restrict__ zh,
        float* __restrict__ a1, float* __restrict__ a2, int M, int GB,
        const int* __restrict__ src, const int* __restrict__ dst,
        int* __restrict__ cnt, int* __restrict__ bucket, int E, int NW, int SB) {
    __shared__ _Float16 Bs[IN_DIM * OUT_DIM];   // 64 KB

    const int t = threadIdx.x;

    if (blockIdx.x >= GB) {
        // ---- scatter block: depth-2 atomic pipeline, grid-stride ----
        const unsigned P = (unsigned)cnt[NW];   // sentinel: never incremented
        const int stride = SB * 512;
        int i = (blockIdx.x - GB) * 512 + t;
        int s0 = 0, d0 = 0;
        unsigned p0 = CAP;
        bool v0 = (i < E);
        if (v0) {
            s0 = src[i]; d0 = dst[i];
            p0 = (unsigned)atomicAdd(&cnt[d0], 1) - P;
        }
        for (int j = i + stride; ; j += stride) {
            bool v1 = (j < E);
            int s1 = 0, d1 = 0;
            unsigned p1 = CAP;
            if (v1) {                         // next edge's atomic issues...
                s1 = src[j]; d1 = dst[j];
                p1 = (unsigned)atomicAdd(&cnt[d1], 1) - P;
            }
            if (v0 && p0 < CAP)               // ...before this one's store waits
                bucket[(size_t)d0 * CAP + p0] = s0;
            if (!v1) break;
            s0 = s1; d0 = d1; p0 = p1; v0 = true;
        }
        return;
    }

    // ---- gemm block ----
    const int lane = t & 63;
    const int w    = t >> 6;          // 0..7
    const int quad = lane >> 4;       // 0..3
    const int l15  = lane & 15;
    const int m0   = blockIdx.x * 256;

    // stage B: read wfc fp32, convert, swizzled ds_write (wconv fused; R10)
#pragma unroll
    for (int i = 0; i < 8; ++i) {
        int idx = t + i * 512;        // granule 0..4095
        int n   = idx >> 5;
        int kb  = idx & 31;
        const float* p = wfc + (size_t)n * IN_DIM + kb * 8;
        float4 q0 = *(const float4*)p;
        float4 q1 = *(const float4*)(p + 4);
        half8_t hv = {(_Float16)q0.x, (_Float16)q0.y, (_Float16)q0.z, (_Float16)q0.w,
                      (_Float16)q1.x, (_Float16)q1.y, (_Float16)q1.z, (_Float16)q1.w};
        *(half8_t*)&Bs[(size_t)(n * 32 + (kb ^ (n & 7))) * 8] = hv;
    }
    __syncthreads();   // the ONLY block-wide barrier

    // lane's two A rows (clamped; OOB rows computed but never stored)
    const int lrow0 = w * 16 + l15;
    const int lrow1 = 128 + w * 16 + l15;
    const int g0 = (m0 + lrow0 < M) ? (m0 + lrow0) : (M - 1);
    const int g1 = (m0 + lrow1 < M) ? (m0 + lrow1) : (M - 1);
    const float* arow0 = h + (size_t)g0 * IN_DIM + quad * 8;
    const float* arow1 = h + (size_t)g1 * IN_DIM + quad * 8;

    f32x4 acc[2][8] = {};   // [row-set][ni]

    // depth-3 rolling A-prefetch (neutral vs R8; kept)
    float4 buf[8][4];
#pragma unroll
    for (int kc = 0; kc < 2; ++kc) {
        buf[kc][0] = *(const float4*)(arow0 + kc * 32);
        buf[kc][1] = *(const float4*)(arow0 + kc * 32 + 4);
        buf[kc][2] = *(const float4*)(arow1 + kc * 32);
        buf[kc][3] = *(const float4*)(arow1 + kc * 32 + 4);
    }
#pragma unroll
    for (int kc = 0; kc < 8; ++kc) {
        if (kc + 2 < 8) {             // issue kc+2's loads before consuming kc
            buf[kc + 2][0] = *(const float4*)(arow0 + (kc + 2) * 32);
            buf[kc + 2][1] = *(const float4*)(arow0 + (kc + 2) * 32 + 4);
            buf[kc + 2][2] = *(const float4*)(arow1 + (kc + 2) * 32);
            buf[kc + 2][3] = *(const float4*)(arow1 + (kc + 2) * 32 + 4);
        }
        float4 cu0 = buf[kc][0], cu1 = buf[kc][1];
        float4 cv0 = buf[kc][2], cv1 = buf[kc][3];
        half8_t a0 = {(_Float16)cu0.x, (_Float16)cu0.y, (_Float16)cu0.z, (_Float16)cu0.w,
                      (_Float16)cu1.x, (_Float16)cu1.y, (_Float16)cu1.z, (_Float16)cu1.w};
        half8_t a1f = {(_Float16)cv0.x, (_Float16)cv0.y, (_Float16)cv0.z, (_Float16)cv0.w,
                       (_Float16)cv1.x, (_Float16)cv1.y, (_Float16)cv1.z, (_Float16)cv1.w};
#pragma unroll
        for (int ni = 0; ni < 8; ++ni) {
            int n = ni * 16 + l15;
            int g = (kc * 4 + quad) ^ (n & 7);
            half8_t b = *(const half8_t*)&Bs[(size_t)(n * 32 + g) * 8];
            acc[0][ni] = __builtin_amdgcn_mfma_f32_16x16x32_f16(a0,  b, acc[0][ni], 0, 0, 0);
            acc[1][ni] = __builtin_amdgcn_mfma_f32_16x16x32_f16(a1f, b, acc[1][ni], 0, 0, 0);
        }
    }

    // ---- fused a1/a2 + z stores (C/D layout col=l15, row=quad*4+r) ----
    float w1v[8], w2v[8];
#pragma unroll
    for (int ni = 0; ni < 8; ++ni) {
        int col = ni * 16 + l15;
        w1v[ni] = wattn[col];
        w2v[ni] = wattn[OUT_DIM + col];
    }
#pragma unroll
    for (int s = 0; s < 2; ++s) {
#pragma unroll
        for (int r = 0; r < 4; ++r) {
            float p1 = 0.f, p2 = 0.f;
#pragma unroll
            for (int ni = 0; ni < 8; ++ni) {
                p1 += acc[s][ni][r] * w1v[ni];
                p2 += acc[s][ni][r] * w2v[ni];
            }
#pragma unroll
            for (int o = 8; o; o >>= 1) {   // reduce across the 16-lane col group
                p1 += __shfl_xor(p1, o);
                p2 += __shfl_xor(p2, o);
            }
            int row = m0 + s * 128 + w * 16 + quad * 4 + r;
            if (row < M) {
                if (l15 == 0) { a1[row] = p1; a2[row] = p2; }
#pragma unroll
                for (int ni = 0; ni < 8; ++ni)
                    zh[(size_t)row * OUT_DIM + ni * 16 + l15] = (_Float16)acc[s][ni][r];
            }
        }
    }
}

// --- K2: agg, 16 lanes per dst, 4-deep batched z-gather (R18, unchanged) ----
__global__ __launch_bounds__(256) void agg_kernel(const _Float16* __restrict__ zh,
                                                  const int* __restrict__ cnt,
                                                  const int* __restrict__ bucket,
                                                  const float* __restrict__ a1,
                                                  const float* __restrict__ a2,
                                                  float* __restrict__ out,
                                                  int NW, int N) {
    const int tid  = threadIdx.x;
    const int lane = tid & 63;
    const int l16  = lane & 15;
    const int w    = (blockIdx.x * 256 + tid) >> 4; // dst = global 16-lane group id
    if (w >= NW) return;

    const unsigned P = (unsigned)cnt[NW];          // sentinel: fill pattern
    unsigned degu = (unsigned)cnt[w] - P;
    int deg = (degu < (unsigned)CAP) ? (int)degu : CAP;
    const float a2w = a2[w];
    const int* brow = bucket + (size_t)w * CAP;
    const int npass = (deg + 15) >> 4;             // 0..4 passes hold slots

    int   se[4];
    float ev[4];
#pragma unroll
    for (int p = 0; p < 4; ++p) {
        se[p] = 0;
        ev[p] = -INFINITY;
        if (p < npass) {                           // group-uniform predicate
            int raw = brow[p * 16 + l16];
            int s   = ((unsigned)raw < (unsigned)N) ? raw : 0;  // clamp poison
            se[p] = s;
            float x = a1[s] + a2w;
            float e = x > 0.f ? x : 0.01f * x;     // leaky_relu(0.01)
            if (e == 0.f) e = -1000.f;             // DGL zero-mask emulation
            if (p * 16 + l16 < deg) ev[p] = e;
        }
    }

    // group softmax
    float mx = fmaxf(fmaxf(ev[0], ev[1]), fmaxf(ev[2], ev[3]));
#pragma unroll
    for (int o = 8; o; o >>= 1) mx = fmaxf(mx, __shfl_xor(mx, o));
    float ex[4];
    float ssum = 0.f;
#pragma unroll
    for (int p = 0; p < 4; ++p) {
        ex[p] = (ev[p] == -INFINITY) ? 0.f : __expf(ev[p] - mx);
        ssum += ex[p];
    }
#pragma unroll
    for (int o = 8; o; o >>= 1) ssum += __shfl_xor(ssum, o);
    const float inv = (deg > 0) ? (1.0f / ssum) : 0.f;
    float al[4];
#pragma unroll
    for (int p = 0; p < 4; ++p) al[p] = ex[p] * inv;

    // weighted aggregation: 4 edges in flight per group per iteration
    const int gbase = lane & 48;                   // group's first lane
    float acc[8] = {0.f, 0.f, 0.f, 0.f, 0.f, 0.f, 0.f, 0.f};
#pragma unroll
    for (int p = 0; p < 4; ++p) {                  // static al/se index
        const int lim = deg - p * 16;              // edges in this pass
        if (lim <= 0) break;
        const int n_e = (lim < 16) ? lim : 16;
        for (int sl = 0; sl < n_e; sl += 4) {
            // slots past n_e have al == 0 exactly (softmax mask) -> no tail loop
            int s1 = sl + 1 < 15 ? sl + 1 : 15;
            int s2 = sl + 2 < 15 ? sl + 2 : 15;
            int s3 = sl + 3 < 15 ? sl + 3 : 15;
            float we0 = __shfl(al[p], gbase | sl);
            float we1 = __shfl(al[p], gbase | s1);
            float we2 = __shfl(al[p], gbase | s2);
            float we3 = __shfl(al[p], gbase | s3);
            int   re0 = __shfl(se[p], gbase | sl);
            int   re1 = __shfl(se[p], gbase | s1);
            int   re2 = __shfl(se[p], gbase | s2);
            int   re3 = __shfl(se[p], gbase | s3);
            half8_t z0 = *(const half8_t*)(zh + (size_t)re0 * OUT_DIM + l16 * 8);
            half8_t z1 = *(const half8_t*)(zh + (size_t)re1 * OUT_DIM + l16 * 8);
            half8_t z2 = *(const half8_t*)(zh + (size_t)re2 * OUT_DIM + l16 * 8);
            half8_t z3 = *(const half8_t*)(zh + (size_t)re3 * OUT_DIM + l16 * 8);
#pragma unroll
            for (int k = 0; k < 8; ++k) {
                float a = acc[k];
                a += we0 * (float)z0[k];
                a += we1 * (float)z1[k];
                a += we2 * (float)z2[k];
                a += we3 * (float)z3[k];
                acc[k] = a;
            }
        }
    }

    // store: 16 lanes x 32B = full 512B row (zeros if deg==0)
    float4 lo = {acc[0], acc[1], acc[2], acc[3]};
    float4 hi = {acc[4], acc[5], acc[6], acc[7]};
    float* op = out + (size_t)w * OUT_DIM + l16 * 8;
    *(float4*)op       = lo;
    *(float4*)(op + 4) = hi;
}

// ---------------------------------------------------------------------------
extern "C" void kernel_launch(void* const* d_in, const int* in_sizes, int n_in,
                              void* d_out, int out_size, void* d_ws, size_t ws_size,
                              hipStream_t stream) {
    const float* h     = (const float*)d_in[0];
    const int*   src   = (const int*)d_in[1];
    const int*   dst   = (const int*)d_in[2];
    const float* wfc   = (const float*)d_in[3];
    const float* wattn = (const float*)d_in[4];
    float*       out   = (float*)d_out;

    const int N  = in_sizes[0] / IN_DIM;   // 100000
    const int E  = in_sizes[1];            // 500000
    const int NW = out_size / OUT_DIM;     // 50000
    const int GB = (N + 255) / 256;        // 391 gemm blocks
    const int SB = 121;                    // 391+121 = 512 = one residency round

    // workspace layout
    _Float16* zh = (_Float16*)d_ws;                      // N*128 f16   (25.6 MB)
    float* a1    = (float*)(zh + (size_t)N * OUT_DIM);   // N
    float* a2    = a1 + N;                               // N
    int*   cnt   = (int*)(a2 + N);                       // NW + 1 sentinel (+pad)
    int*   bucket = cnt + NW + 8;                        // NW*CAP ints (12.8 MB)

    gemm_scatter_kernel<<<GB + SB, 512, 0, stream>>>(h, wfc, wattn, zh, a1, a2, N, GB,
                                                     src, dst, cnt, bucket, E, NW, SB);
    agg_kernel<<<(NW + 15) / 16, 256, 0, stream>>>(zh, cnt, bucket, a1, a2, out, NW, N);
}

// Round 14
// 212.299 us; speedup vs baseline: 1.0141x; 1.0141x over previous
//
#include <hip/hip_runtime.h>
#include <cstddef>
#include <cmath>

// ---------------------------------------------------------------------------
// SWGAT layer:
//   z = h @ W_fc.T                       [N,128]
//   e = leaky_relu(a1[src] + a2[dst]);  e==0 -> -1000
//   segment softmax over dst, out[w] = sum alpha * z[src]
// R20 (FINAL): revert to R18, the session best (213.7us; R19's co-resident
//      scatter was neutral at 215.3). Session converged: across R8-R19 every
//      structural axis was varied singly -- gemm staging (LDS/2-phase/none),
//      prefetch depth (1/2/3), scatter shape (trailing/co-resident/replicated
//      /pipelined), agg parallelization (64-lane/16-lane/batched), pipeline
//      depth (9/4/3/2 dispatches) -- and everything lands within +-2us of
//      this structure, while regressions (R9 2-phase, R11 replicas, R16
//      LDS-free) cost 10-115us. Remaining budget: harness fill ~60us
//      (untouchable), fused ~70, agg ~60, boundary ~15: latency-bound
//      plateau, not a counter-visible roofline; hypothesis queue empty.
// Structure: 2 dispatches.
//   K1 = fused Bconv+gemm (256-row tile, 64KB swizzled f16 B in LDS, depth-3
//        A prefetch, fused a1/a2 epilogue) + trailing scatter (1 edge/thr,
//        poison-baseline cnt -- no memset needed).
//   K2 = agg, 16 lanes/dst, 4-deep batched z-gather.
// ---------------------------------------------------------------------------

#define IN_DIM  256
#define OUT_DIM 128
#define CAP     64      // max edges kept per dst (Poisson(10) => max deg ~30)

typedef _Float16 half2_t __attribute__((ext_vector_type(2)));
typedef _Float16 half8_t __attribute__((ext_vector_type(8)));
typedef float    f32x4   __attribute__((ext_vector_type(4)));

// --- K1: fused Bconv + gemm + scatter ---------------------------------------
// Blocks [0, GB): gemm. 512 thr = 8 waves, tile 256 rows x 128 cols. B staged
//   by reading wfc fp32 (L2-hot after first blocks), converting to f16 and
//   ds_write-ing swizzled granules: granule g = n*32+(kb^(n&7)) holds
//   W[n][kb*8..+7]. Wave w owns rows {w*16..+15},{128+w*16..+15}; depth-3
//   rolling A prefetch; one barrier.
// Blocks [GB, GB+SB): scatter, 1 edge/thread, poison-baseline slot index.
__global__ __launch_bounds__(512, 4) void gemm_scatter_kernel(
        const float* __restrict__ h, const float* __restrict__ wfc,
        const float* __restrict__ wattn, _Float16* __restrict__ zh,
        float* __restrict__ a1, float* __restrict__ a2, int M, int GB,
        const int* __restrict__ src, const int* __restrict__ dst,
        int* __restrict__ cnt, int* __restrict__ bucket, int E, int NW) {
    __shared__ _Float16 Bs[IN_DIM * OUT_DIM];   // 64 KB

    const int t = threadIdx.x;

    if (blockIdx.x >= GB) {
        // ---- scatter block: slot relative to poison baseline P ----
        const unsigned P = (unsigned)cnt[NW];   // sentinel: never incremented
        int i = (blockIdx.x - GB) * 512 + t;
        if (i < E) {
            int s = src[i];
            int d = dst[i];
            unsigned pos = (unsigned)atomicAdd(&cnt[d], 1) - P;
            if (pos < CAP)                      // overflow guard (never hit here)
                bucket[(size_t)d * CAP + pos] = s;
        }
        return;
    }

    // ---- gemm block ----
    const int lane = t & 63;
    const int w    = t >> 6;          // 0..7
    const int quad = lane >> 4;       // 0..3
    const int l15  = lane & 15;
    const int m0   = blockIdx.x * 256;

    // stage B: read wfc fp32, convert, swizzled ds_write (wconv fused; R10)
#pragma unroll
    for (int i = 0; i < 8; ++i) {
        int idx = t + i * 512;        // granule 0..4095
        int n   = idx >> 5;
        int kb  = idx & 31;
        const float* p = wfc + (size_t)n * IN_DIM + kb * 8;
        float4 q0 = *(const float4*)p;
        float4 q1 = *(const float4*)(p + 4);
        half8_t hv = {(_Float16)q0.x, (_Float16)q0.y, (_Float16)q0.z, (_Float16)q0.w,
                      (_Float16)q1.x, (_Float16)q1.y, (_Float16)q1.z, (_Float16)q1.w};
        *(half8_t*)&Bs[(size_t)(n * 32 + (kb ^ (n & 7))) * 8] = hv;
    }
    __syncthreads();   // the ONLY block-wide barrier

    // lane's two A rows (clamped; OOB rows computed but never stored)
    const int lrow0 = w * 16 + l15;
    const int lrow1 = 128 + w * 16 + l15;
    const int g0 = (m0 + lrow0 < M) ? (m0 + lrow0) : (M - 1);
    const int g1 = (m0 + lrow1 < M) ? (m0 + lrow1) : (M - 1);
    const float* arow0 = h + (size_t)g0 * IN_DIM + quad * 8;
    const float* arow1 = h + (size_t)g1 * IN_DIM + quad * 8;

    f32x4 acc[2][8] = {};   // [row-set][ni]

    // depth-3 rolling A-prefetch (neutral vs R8; kept)
    float4 buf[8][4];
#pragma unroll
    for (int kc = 0; kc < 2; ++kc) {
        buf[kc][0] = *(const float4*)(arow0 + kc * 32);
        buf[kc][1] = *(const float4*)(arow0 + kc * 32 + 4);
        buf[kc][2] = *(const float4*)(arow1 + kc * 32);
        buf[kc][3] = *(const float4*)(arow1 + kc * 32 + 4);
    }
#pragma unroll
    for (int kc = 0; kc < 8; ++kc) {
        if (kc + 2 < 8) {             // issue kc+2's loads before consuming kc
            buf[kc + 2][0] = *(const float4*)(arow0 + (kc + 2) * 32);
            buf[kc + 2][1] = *(const float4*)(arow0 + (kc + 2) * 32 + 4);
            buf[kc + 2][2] = *(const float4*)(arow1 + (kc + 2) * 32);
            buf[kc + 2][3] = *(const float4*)(arow1 + (kc + 2) * 32 + 4);
        }
        float4 cu0 = buf[kc][0], cu1 = buf[kc][1];
        float4 cv0 = buf[kc][2], cv1 = buf[kc][3];
        half8_t a0 = {(_Float16)cu0.x, (_Float16)cu0.y, (_Float16)cu0.z, (_Float16)cu0.w,
                      (_Float16)cu1.x, (_Float16)cu1.y, (_Float16)cu1.z, (_Float16)cu1.w};
        half8_t a1f = {(_Float16)cv0.x, (_Float16)cv0.y, (_Float16)cv0.z, (_Float16)cv0.w,
                       (_Float16)cv1.x, (_Float16)cv1.y, (_Float16)cv1.z, (_Float16)cv1.w};
#pragma unroll
        for (int ni = 0; ni < 8; ++ni) {
            int n = ni * 16 + l15;
            int g = (kc * 4 + quad) ^ (n & 7);
            half8_t b = *(const half8_t*)&Bs[(size_t)(n * 32 + g) * 8];
            acc[0][ni] = __builtin_amdgcn_mfma_f32_16x16x32_f16(a0,  b, acc[0][ni], 0, 0, 0);
            acc[1][ni] = __builtin_amdgcn_mfma_f32_16x16x32_f16(a1f, b, acc[1][ni], 0, 0, 0);
        }
    }

    // ---- fused a1/a2 + z stores (C/D layout col=l15, row=quad*4+r) ----
    float w1v[8], w2v[8];
#pragma unroll
    for (int ni = 0; ni < 8; ++ni) {
        int col = ni * 16 + l15;
        w1v[ni] = wattn[col];
        w2v[ni] = wattn[OUT_DIM + col];
    }
#pragma unroll
    for (int s = 0; s < 2; ++s) {
#pragma unroll
        for (int r = 0; r < 4; ++r) {
            float p1 = 0.f, p2 = 0.f;
#pragma unroll
            for (int ni = 0; ni < 8; ++ni) {
                p1 += acc[s][ni][r] * w1v[ni];
                p2 += acc[s][ni][r] * w2v[ni];
            }
#pragma unroll
            for (int o = 8; o; o >>= 1) {   // reduce across the 16-lane col group
                p1 += __shfl_xor(p1, o);
                p2 += __shfl_xor(p2, o);
            }
            int row = m0 + s * 128 + w * 16 + quad * 4 + r;
            if (row < M) {
                if (l15 == 0) { a1[row] = p1; a2[row] = p2; }
#pragma unroll
                for (int ni = 0; ni < 8; ++ni)
                    zh[(size_t)row * OUT_DIM + ni * 16 + l15] = (_Float16)acc[s][ni][r];
            }
        }
    }
}

// --- K2: agg, 16 lanes per dst, 4-deep batched z-gather ---------------------
// deg = cnt[w] - P (poison baseline). Group g = lanes [g*16,g*16+16) owns dst
// w. Bucket row read in <=4 passes of 16 slots; e = lrelu(a1[src]+a2[w]).
// Softmax: per-lane max/sum over 4 register slots + 4 shfl_xor rounds.
// Aggregation: 4 edges per iteration -- 8 shfls, then 4 INDEPENDENT 16B
// z-loads in flight per group, then FMAs. Slot index clamps to 15; weights
// of edges past deg are exactly 0 (softmax-masked al), so no remainder loop
// and per-acc accumulation order matches the serial version bit-for-bit.
__global__ __launch_bounds__(256) void agg_kernel(const _Float16* __restrict__ zh,
                                                  const int* __restrict__ cnt,
                                                  const int* __restrict__ bucket,
                                                  const float* __restrict__ a1,
                                                  const float* __restrict__ a2,
                                                  float* __restrict__ out,
                                                  int NW, int N) {
    const int tid  = threadIdx.x;
    const int lane = tid & 63;
    const int l16  = lane & 15;
    const int w    = (blockIdx.x * 256 + tid) >> 4; // dst = global 16-lane group id
    if (w >= NW) return;

    const unsigned P = (unsigned)cnt[NW];          // sentinel: fill pattern
    unsigned degu = (unsigned)cnt[w] - P;
    int deg = (degu < (unsigned)CAP) ? (int)degu : CAP;
    const float a2w = a2[w];
    const int* brow = bucket + (size_t)w * CAP;
    const int npass = (deg + 15) >> 4;             // 0..4 passes hold slots

    int   se[4];
    float ev[4];
#pragma unroll
    for (int p = 0; p < 4; ++p) {
        se[p] = 0;
        ev[p] = -INFINITY;
        if (p < npass) {                           // group-uniform predicate
            int raw = brow[p * 16 + l16];
            int s   = ((unsigned)raw < (unsigned)N) ? raw : 0;  // clamp poison
            se[p] = s;
            float x = a1[s] + a2w;
            float e = x > 0.f ? x : 0.01f * x;     // leaky_relu(0.01)
            if (e == 0.f) e = -1000.f;             // DGL zero-mask emulation
            if (p * 16 + l16 < deg) ev[p] = e;
        }
    }

    // group softmax
    float mx = fmaxf(fmaxf(ev[0], ev[1]), fmaxf(ev[2], ev[3]));
#pragma unroll
    for (int o = 8; o; o >>= 1) mx = fmaxf(mx, __shfl_xor(mx, o));
    float ex[4];
    float ssum = 0.f;
#pragma unroll
    for (int p = 0; p < 4; ++p) {
        ex[p] = (ev[p] == -INFINITY) ? 0.f : __expf(ev[p] - mx);
        ssum += ex[p];
    }
#pragma unroll
    for (int o = 8; o; o >>= 1) ssum += __shfl_xor(ssum, o);
    const float inv = (deg > 0) ? (1.0f / ssum) : 0.f;
    float al[4];
#pragma unroll
    for (int p = 0; p < 4; ++p) al[p] = ex[p] * inv;

    // weighted aggregation: 4 edges in flight per group per iteration
    const int gbase = lane & 48;                   // group's first lane
    float acc[8] = {0.f, 0.f, 0.f, 0.f, 0.f, 0.f, 0.f, 0.f};
#pragma unroll
    for (int p = 0; p < 4; ++p) {                  // static al/se index
        const int lim = deg - p * 16;              // edges in this pass
        if (lim <= 0) break;
        const int n_e = (lim < 16) ? lim : 16;
        for (int sl = 0; sl < n_e; sl += 4) {
            // slots past n_e have al == 0 exactly (softmax mask) -> no tail loop
            int s1 = sl + 1 < 15 ? sl + 1 : 15;
            int s2 = sl + 2 < 15 ? sl + 2 : 15;
            int s3 = sl + 3 < 15 ? sl + 3 : 15;
            float we0 = __shfl(al[p], gbase | sl);
            float we1 = __shfl(al[p], gbase | s1);
            float we2 = __shfl(al[p], gbase | s2);
            float we3 = __shfl(al[p], gbase | s3);
            int   re0 = __shfl(se[p], gbase | sl);
            int   re1 = __shfl(se[p], gbase | s1);
            int   re2 = __shfl(se[p], gbase | s2);
            int   re3 = __shfl(se[p], gbase | s3);
            half8_t z0 = *(const half8_t*)(zh + (size_t)re0 * OUT_DIM + l16 * 8);
            half8_t z1 = *(const half8_t*)(zh + (size_t)re1 * OUT_DIM + l16 * 8);
            half8_t z2 = *(const half8_t*)(zh + (size_t)re2 * OUT_DIM + l16 * 8);
            half8_t z3 = *(const half8_t*)(zh + (size_t)re3 * OUT_DIM + l16 * 8);
#pragma unroll
            for (int k = 0; k < 8; ++k) {
                float a = acc[k];
                a += we0 * (float)z0[k];
                a += we1 * (float)z1[k];
                a += we2 * (float)z2[k];
                a += we3 * (float)z3[k];
                acc[k] = a;
            }
        }
    }

    // store: 16 lanes x 32B = full 512B row (zeros if deg==0)
    float4 lo = {acc[0], acc[1], acc[2], acc[3]};
    float4 hi = {acc[4], acc[5], acc[6], acc[7]};
    float* op = out + (size_t)w * OUT_DIM + l16 * 8;
    *(float4*)op       = lo;
    *(float4*)(op + 4) = hi;
}

// ---------------------------------------------------------------------------
extern "C" void kernel_launch(void* const* d_in, const int* in_sizes, int n_in,
                              void* d_out, int out_size, void* d_ws, size_t ws_size,
                              hipStream_t stream) {
    const float* h     = (const float*)d_in[0];
    const int*   src   = (const int*)d_in[1];
    const int*   dst   = (const int*)d_in[2];
    const float* wfc   = (const float*)d_in[3];
    const float* wattn = (const float*)d_in[4];
    float*       out   = (float*)d_out;

    const int N  = in_sizes[0] / IN_DIM;   // 100000
    const int E  = in_sizes[1];            // 500000
    const int NW = out_size / OUT_DIM;     // 50000
    const int GB = (N + 255) / 256;        // 391 gemm blocks
    const int SB = (E + 511) / 512;        // 977 scatter blocks (trailing)

    // workspace layout
    _Float16* zh = (_Float16*)d_ws;                      // N*128 f16   (25.6 MB)
    float* a1    = (float*)(zh + (size_t)N * OUT_DIM);   // N
    float* a2    = a1 + N;                               // N
    int*   cnt   = (int*)(a2 + N);                       // NW + 1 sentinel (+pad)
    int*   bucket = cnt + NW + 8;                        // NW*CAP ints (12.8 MB)

    gemm_scatter_kernel<<<GB + SB, 512, 0, stream>>>(h, wfc, wattn, zh, a1, a2, N, GB,
                                                     src, dst, cnt, bucket, E, NW);
    agg_kernel<<<(NW + 15) / 16, 256, 0, stream>>>(zh, cnt, bucket, a1, a2, out, NW, N);
}